// Round 6
// baseline (109.616 us; speedup 1.0000x reference)
//
#include <hip/hip_runtime.h>

typedef __attribute__((ext_vector_type(4))) float f32x4;
typedef __attribute__((ext_vector_type(4))) int i32x4;
typedef __attribute__((ext_vector_type(8))) short short8;
typedef unsigned int u32;
typedef unsigned long long u64;
typedef unsigned short u16;

#define NB 512
#define TT 256
#define CC 384
#define HH 64

__device__ __forceinline__ u16 fbf(float f) {
    u32 u = __builtin_bit_cast(u32, f);
    u32 r = u + 0x7fffu + ((u >> 16) & 1u);
    return (u16)(r >> 16);
}

// pack two f32 -> two bf16 (RNE) in one instruction
__device__ __forceinline__ u32 cvtpk(float lo, float hi) {
    u32 r;
    asm("v_cvt_pk_bf16_f32 %0, %1, %2" : "=v"(r) : "v"(lo), "v"(hi));
    return r;
}

__device__ __forceinline__ f32x4 mfma16x16x32(short8 a, short8 b, f32x4 c) {
    return __builtin_amdgcn_mfma_f32_16x16x32_bf16(a, b, c, 0, 0, 0);
}

__device__ __forceinline__ short8 load_afr(const float* p) {
    f32x4 f0 = *(const f32x4*)p;
    f32x4 f1 = *(const f32x4*)(p + 4);
    i32x4 aw = {(int)cvtpk(f0[0], f0[1]), (int)cvtpk(f0[2], f0[3]),
                (int)cvtpk(f1[0], f1[1]), (int)cvtpk(f1[2], f1[3])};
    return __builtin_bit_cast(short8, aw);
}

// WbT layout: fragment fi = ((mat*12 + kt)*4 + nt); element (fi*64 + lane)*8 + j
//   = W[mat][c = 32*kt + 8*(lane>>4) + j][h = 16*nt + (lane&15)]
// mat 0 = Wq * 384^-0.5 (scale folded), 1 = Wk, 2 = Wv.
__global__ __launch_bounds__(256) void prep_w(const float* __restrict__ Wk,
                                              const float* __restrict__ Wq,
                                              const float* __restrict__ Wv,
                                              u16* __restrict__ WbT) {
    int t = blockIdx.x * 256 + threadIdx.x;
    if (t >= 144 * 64) return;
    int lane = t & 63;
    int fi = t >> 6;
    int mat = fi / 48;
    int kt = (fi >> 2) % 12;
    int nt = fi & 3;
    const float* W = (mat == 0) ? Wq : (mat == 1 ? Wk : Wv);
    float scale = (mat == 0) ? 0.05103103630798288f : 1.0f;
    int c0 = 32 * kt + 8 * (lane >> 4);
    int h = 16 * nt + (lane & 15);
#pragma unroll
    for (int j = 0; j < 8; ++j)
        WbT[(size_t)t * 8 + j] = fbf(W[(c0 + j) * HH + h] * scale);
}

// One block per batch, 8 waves, LDS 80KB -> 2 blocks/CU.
// Wave w owns two 16-row q-tiles: gr0=16w and gr1=240-16w (balanced causal
// work: 5 tile-chunks per wave). Projection: two passes (A: Q+K both tiles,
// B: V both tiles) -- WbT read once per wave. Attention: the two tiles are
// INTERLEAVED in one chunk loop (2x ILP in the latency-bound QK/softmax
// phase; K-fragments loaded once, shared by both tiles); tile guards are
// wave-uniform (depend only on w). PV per tile via shared 2KB/wave scratch.
// NOTE: PV reads P s-blocks st <= (stmax|1); P writes MUST cover that range
// (zeros beyond stmax) -- reading unwritten LDS was round-3's NaN.
// NOTE: __launch_bounds__ min-arg acts like blocks/CU on this toolchain:
// (512,4) capped VGPRs at 64 and spilled (r2/r4); (512,2) -> cap 128 (r5 ok).
__global__ __launch_bounds__(512, 2) void attn_head(const float* __restrict__ x,
                                                    const u16* __restrict__ WbT,
                                                    float* __restrict__ out) {
    __shared__ __align__(16) u16 Klds[TT * HH];      // 32 KB
    __shared__ __align__(16) u16 Vtlds[HH * TT];     // 32 KB
    __shared__ __align__(16) u16 Pscr[8 * 16 * 64];  // 16 KB

    const int tid = (int)threadIdx.x;
    const int lane = tid & 63;
    const int w = tid >> 6;
    const int c = lane & 15;
    const int g = lane >> 4;
    const int b = (int)blockIdx.x;
    const int gr0 = 16 * w;
    const int gr1 = 240 - 16 * w;

    char* kbase = (char*)Klds;
    char* vbase = (char*)Vtlds;
    char* sbase = (char*)(Pscr + w * 1024);
    const float* xb = x + (size_t)b * TT * CC;
    const float* prow0 = xb + (size_t)(gr0 + c) * CC + 8 * g;
    const float* prow1 = xb + (size_t)(gr1 + c) * CC + 8 * g;

    short8 Qf[2][2];

    // ---------------- pass A: Q and K for both tiles ----------------
    {
        f32x4 acc[2][2][4];  // [mat Q/K][tile][nt]
#pragma unroll
        for (int m = 0; m < 2; ++m)
#pragma unroll
            for (int t = 0; t < 2; ++t)
#pragma unroll
                for (int nt = 0; nt < 4; ++nt)
                    acc[m][t][nt] = (f32x4){0.f, 0.f, 0.f, 0.f};

        for (int kt = 0; kt < 12; ++kt) {
            short8 a0 = load_afr(prow0 + 32 * kt);
            short8 a1 = load_afr(prow1 + 32 * kt);
#pragma unroll
            for (int mat = 0; mat < 2; ++mat)
#pragma unroll
                for (int nt = 0; nt < 4; ++nt) {
                    short8 bfr = *(const short8*)(WbT + (size_t)(((mat * 12 + kt) * 4 + nt) * 64 + lane) * 8);
                    acc[mat][0][nt] = mfma16x16x32(a0, bfr, acc[mat][0][nt]);
                    acc[mat][1][nt] = mfma16x16x32(a1, bfr, acc[mat][1][nt]);
                }
        }

        // Q: D-layout -> own K rows (scratch) -> B-fragments, per tile
#pragma unroll
        for (int t = 0; t < 2; ++t) {
            const int gr = t ? gr1 : gr0;
#pragma unroll
            for (int nt = 0; nt < 4; ++nt)
#pragma unroll
                for (int r = 0; r < 4; ++r) {
                    int q = gr + 4 * g + r;
                    int hh = 16 * nt + c;
                    *(u16*)(kbase + q * 128 + ((hh * 2) ^ ((q & 7) << 4))) = fbf(acc[0][t][nt][r]);
                }
#pragma unroll
            for (int kt = 0; kt < 2; ++kt) {
                int q = gr + c;
                Qf[t][kt] = *(const short8*)(kbase + q * 128 + ((64 * kt + 16 * g) ^ ((q & 7) << 4)));
            }
        }

        // K rows (overwrite Q scratch; same-wave DS ordering is program order)
#pragma unroll
        for (int t = 0; t < 2; ++t) {
            const int gr = t ? gr1 : gr0;
#pragma unroll
            for (int nt = 0; nt < 4; ++nt) {
                int hh = 16 * nt + c;
#pragma unroll
                for (int r = 0; r < 4; ++r) {
                    int s = gr + 4 * g + r;
                    *(u16*)(kbase + s * 128 + ((hh * 2) ^ ((s & 7) << 4))) = fbf(acc[1][t][nt][r]);
                }
            }
        }
    }

    // ---------------- pass B: V for both tiles ----------------
    {
        f32x4 accV[2][4];
#pragma unroll
        for (int t = 0; t < 2; ++t)
#pragma unroll
            for (int nt = 0; nt < 4; ++nt)
                accV[t][nt] = (f32x4){0.f, 0.f, 0.f, 0.f};

        for (int kt = 0; kt < 12; ++kt) {
            short8 a0 = load_afr(prow0 + 32 * kt);
            short8 a1 = load_afr(prow1 + 32 * kt);
#pragma unroll
            for (int nt = 0; nt < 4; ++nt) {
                short8 bfr = *(const short8*)(WbT + (size_t)(((2 * 12 + kt) * 4 + nt) * 64 + lane) * 8);
                accV[0][nt] = mfma16x16x32(a0, bfr, accV[0][nt]);
                accV[1][nt] = mfma16x16x32(a1, bfr, accV[1][nt]);
            }
        }

#pragma unroll
        for (int t = 0; t < 2; ++t) {
            const int gr = t ? gr1 : gr0;
#pragma unroll
            for (int nt = 0; nt < 4; ++nt) {
                int hh = 16 * nt + c;
                int sb4 = gr + 4 * g;
                u64 pkv = (u64)cvtpk(accV[t][nt][0], accV[t][nt][1]) |
                          ((u64)cvtpk(accV[t][nt][2], accV[t][nt][3]) << 32);
                *(u64*)(vbase + hh * 512 + ((sb4 * 2) ^ ((hh & 7) << 4))) = pkv;
            }
        }
    }

    __syncthreads();

    // ---------------- attention: two tiles interleaved ----------------
    const int lastc0 = (gr0 + 15) >> 6;
    const int lastc1 = (gr1 + 15) >> 6;  // always >= lastc0 (gr1 > gr0+15)
    const int qg0 = gr0 + c, qg1 = gr1 + c;

    float m0r = -1e30f, l0r = 0.f, m1r = -1e30f, l1r = 0.f;
    f32x4 o0[4], o1[4];
#pragma unroll
    for (int ht = 0; ht < 4; ++ht) {
        o0[ht] = (f32x4){0.f, 0.f, 0.f, 0.f};
        o1[ht] = (f32x4){0.f, 0.f, 0.f, 0.f};
    }

    for (int ci = 0; ci <= lastc1; ++ci) {
        const int s0 = 64 * ci;
        const bool a0v = (ci <= lastc0);  // wave-uniform
        int stx0 = a0v ? ((gr0 + 15 - s0) >> 4) : -1;
        const int stmax0 = stx0 > 3 ? 3 : stx0;
        int stx1 = (gr1 + 15 - s0) >> 4;
        const int stmax1 = stx1 > 3 ? 3 : stx1;  // >= stmax0, >= 0
        const bool mask0 = a0v && (s0 + 63 > gr0);
        const bool mask1 = (s0 + 63 > gr1);

        // S^T: K-fragment loaded once, shared by both tiles
        f32x4 SS0[4], SS1[4];
#pragma unroll
        for (int st = 0; st < 4; ++st) {
            SS0[st] = (f32x4){0.f, 0.f, 0.f, 0.f};
            SS1[st] = (f32x4){0.f, 0.f, 0.f, 0.f};
        }
#pragma unroll
        for (int kt = 0; kt < 2; ++kt)
#pragma unroll
            for (int st = 0; st < 4; ++st)
                if (st <= stmax1) {
                    int s = s0 + 16 * st + c;
                    short8 kf = *(const short8*)(kbase + s * 128 + ((64 * kt + 16 * g) ^ ((s & 7) << 4)));
                    SS1[st] = mfma16x16x32(kf, Qf[1][kt], SS1[st]);
                    if (st <= stmax0) SS0[st] = mfma16x16x32(kf, Qf[0][kt], SS0[st]);
                }

        // mask + chunk max (two independent chains)
        float mx0 = -1e30f, mx1 = -1e30f;
#pragma unroll
        for (int st = 0; st < 4; ++st) {
#pragma unroll
            for (int r = 0; r < 4; ++r) {
                int sg = s0 + 16 * st + 4 * g + r;
                if (st <= stmax0) {
                    float v = SS0[st][r];
                    if (mask0) { v = (sg > qg0) ? -1e30f : v; SS0[st][r] = v; }
                    mx0 = fmaxf(mx0, v);
                }
                if (st <= stmax1) {
                    float v = SS1[st][r];
                    if (mask1) { v = (sg > qg1) ? -1e30f : v; SS1[st][r] = v; }
                    mx1 = fmaxf(mx1, v);
                }
            }
        }
        if (a0v) {
            mx0 = fmaxf(mx0, __shfl_xor(mx0, 16));
            mx0 = fmaxf(mx0, __shfl_xor(mx0, 32));
        }
        mx1 = fmaxf(mx1, __shfl_xor(mx1, 16));
        mx1 = fmaxf(mx1, __shfl_xor(mx1, 32));

        float fs0 = 1.f, fs1;
        if (a0v) {
            float mn = fmaxf(m0r, mx0);
            fs0 = __expf(m0r - mn);
            m0r = mn;
        }
        {
            float mn = fmaxf(m1r, mx1);
            fs1 = __expf(m1r - mn);
            m1r = mn;
        }

        float ls0 = 0.f, ls1 = 0.f;
#pragma unroll
        for (int st = 0; st < 4; ++st)
#pragma unroll
            for (int r = 0; r < 4; ++r) {
                if (st <= stmax0) {
                    float p = __expf(SS0[st][r] - m0r);
                    SS0[st][r] = p;
                    ls0 += p;
                }
                if (st <= stmax1) {
                    float p = __expf(SS1[st][r] - m1r);
                    SS1[st][r] = p;
                    ls1 += p;
                }
            }
        if (a0v) {
            ls0 += __shfl_xor(ls0, 16);
            ls0 += __shfl_xor(ls0, 32);
            l0r = l0r * fs0 + ls0;
        }
        ls1 += __shfl_xor(ls1, 16);
        ls1 += __shfl_xor(ls1, 32);
        l1r = l1r * fs1 + ls1;

        // rescale O accumulators (row j=4g+r gets fs from lane c'=j)
        if (ci) {
#pragma unroll
            for (int r = 0; r < 4; ++r) {
                float fr0 = __shfl(fs0, 4 * g + r);
                float fr1 = __shfl(fs1, 4 * g + r);
#pragma unroll
                for (int ht = 0; ht < 4; ++ht) {
                    if (a0v) o0[ht][r] *= fr0;
                    o1[ht][r] *= fr1;
                }
            }
        }

        // ---- PV tile0 via shared scratch (same-wave DS ordering protects reuse) ----
        if (a0v) {
            const int stW = stmax0 | 1;
#pragma unroll
            for (int st = 0; st < 4; ++st)
                if (st <= stW) {
                    u64 pp = 0;
                    if (st <= stmax0)
                        pp = (u64)cvtpk(SS0[st][0], SS0[st][1]) |
                             ((u64)cvtpk(SS0[st][2], SS0[st][3]) << 32);
                    *(u64*)(sbase + c * 128 + ((32 * st + 8 * g) ^ ((c & 7) << 4))) = pp;
                }
            const int ksmax = stmax0 >> 1;
#pragma unroll
            for (int ks = 0; ks < 2; ++ks)
                if (ks <= ksmax) {
                    short8 Pf = *(const short8*)(sbase + c * 128 + ((64 * ks + 16 * g) ^ ((c & 7) << 4)));
#pragma unroll
                    for (int ht = 0; ht < 4; ++ht) {
                        int hh = 16 * ht + c;
                        short8 vf = *(const short8*)(vbase + hh * 512 + ((2 * s0 + 64 * ks + 16 * g) ^ ((hh & 7) << 4)));
                        o0[ht] = mfma16x16x32(Pf, vf, o0[ht]);
                    }
                }
        }

        // ---- PV tile1 ----
        {
            const int stW = stmax1 | 1;
#pragma unroll
            for (int st = 0; st < 4; ++st)
                if (st <= stW) {
                    u64 pp = 0;
                    if (st <= stmax1)
                        pp = (u64)cvtpk(SS1[st][0], SS1[st][1]) |
                             ((u64)cvtpk(SS1[st][2], SS1[st][3]) << 32);
                    *(u64*)(sbase + c * 128 + ((32 * st + 8 * g) ^ ((c & 7) << 4))) = pp;
                }
            const int ksmax = stmax1 >> 1;
#pragma unroll
            for (int ks = 0; ks < 2; ++ks)
                if (ks <= ksmax) {
                    short8 Pf = *(const short8*)(sbase + c * 128 + ((64 * ks + 16 * g) ^ ((c & 7) << 4)));
#pragma unroll
                    for (int ht = 0; ht < 4; ++ht) {
                        int hh = 16 * ht + c;
                        short8 vf = *(const short8*)(vbase + hh * 512 + ((2 * s0 + 64 * ks + 16 * g) ^ ((hh & 7) << 4)));
                        o1[ht] = mfma16x16x32(Pf, vf, o1[ht]);
                    }
                }
        }
    }

    // ---------------- epilogue: both tiles ----------------
    float ri0 = 1.f / l0r, ri1 = 1.f / l1r;
    float* ob0 = out + ((size_t)b * TT + gr0) * HH;
    float* ob1 = out + ((size_t)b * TT + gr1) * HH;
#pragma unroll
    for (int r = 0; r < 4; ++r) {
        float rr0 = __shfl(ri0, 4 * g + r);
        float rr1 = __shfl(ri1, 4 * g + r);
#pragma unroll
        for (int ht = 0; ht < 4; ++ht) {
            ob0[(4 * g + r) * HH + 16 * ht + c] = o0[ht][r] * rr0;
            ob1[(4 * g + r) * HH + 16 * ht + c] = o1[ht][r] * rr1;
        }
    }
}

extern "C" void kernel_launch(void* const* d_in, const int* in_sizes, int n_in,
                              void* d_out, int out_size, void* d_ws, size_t ws_size,
                              hipStream_t stream) {
    (void)in_sizes; (void)n_in; (void)out_size; (void)ws_size;
    const float* x = (const float*)d_in[0];
    const float* Wk = (const float*)d_in[1];
    const float* Wq = (const float*)d_in[2];
    const float* Wv = (const float*)d_in[3];
    u16* WbT = (u16*)d_ws;
    float* out = (float*)d_out;

    prep_w<<<36, 256, 0, stream>>>(Wk, Wq, Wv, WbT);
    attn_head<<<NB, 512, 0, stream>>>(x, WbT, out);
}

// Round 7
// 97.443 us; speedup vs baseline: 1.1249x; 1.1249x over previous
//
#include <hip/hip_runtime.h>

typedef __attribute__((ext_vector_type(4))) float f32x4;
typedef __attribute__((ext_vector_type(4))) int i32x4;
typedef __attribute__((ext_vector_type(8))) short short8;
typedef unsigned int u32;
typedef unsigned long long u64;
typedef unsigned short u16;

#define NB 512
#define TT 256
#define CC 384
#define HH 64

__device__ __forceinline__ u16 fbf(float f) {
    u32 u = __builtin_bit_cast(u32, f);
    u32 r = u + 0x7fffu + ((u >> 16) & 1u);
    return (u16)(r >> 16);
}

// pack two f32 -> two bf16 (RNE) in one instruction
__device__ __forceinline__ u32 cvtpk(float lo, float hi) {
    u32 r;
    asm("v_cvt_pk_bf16_f32 %0, %1, %2" : "=v"(r) : "v"(lo), "v"(hi));
    return r;
}

__device__ __forceinline__ f32x4 mfma16x16x32(short8 a, short8 b, f32x4 c) {
    return __builtin_amdgcn_mfma_f32_16x16x32_bf16(a, b, c, 0, 0, 0);
}

__device__ __forceinline__ short8 load_afr(const float* p) {
    f32x4 f0 = *(const f32x4*)p;
    f32x4 f1 = *(const f32x4*)(p + 4);
    i32x4 aw = {(int)cvtpk(f0[0], f0[1]), (int)cvtpk(f0[2], f0[3]),
                (int)cvtpk(f1[0], f1[1]), (int)cvtpk(f1[2], f1[3])};
    return __builtin_bit_cast(short8, aw);
}

// WbT layout: fragment fi = ((mat*12 + kt)*4 + nt); element (fi*64 + lane)*8 + j
//   = W[mat][c = 32*kt + 8*(lane>>4) + j][h = 16*nt + (lane&15)]
// mat 0 = Wq * 384^-0.5 (scale folded), 1 = Wk, 2 = Wv.
__global__ __launch_bounds__(256) void prep_w(const float* __restrict__ Wk,
                                              const float* __restrict__ Wq,
                                              const float* __restrict__ Wv,
                                              u16* __restrict__ WbT) {
    int t = blockIdx.x * 256 + threadIdx.x;
    if (t >= 144 * 64) return;
    int lane = t & 63;
    int fi = t >> 6;
    int mat = fi / 48;
    int kt = (fi >> 2) % 12;
    int nt = fi & 3;
    const float* W = (mat == 0) ? Wq : (mat == 1 ? Wk : Wv);
    float scale = (mat == 0) ? 0.05103103630798288f : 1.0f;
    int c0 = 32 * kt + 8 * (lane >> 4);
    int h = 16 * nt + (lane & 15);
#pragma unroll
    for (int j = 0; j < 8; ++j)
        WbT[(size_t)t * 8 + j] = fbf(W[(c0 + j) * HH + h] * scale);
}

// One block per batch, 8 waves, LDS 80KB -> 2 blocks/CU (needs arch+acc
// VGPR <= 128: rocprof VGPR_Count is ARCH only, MFMA accumulators (AGPR)
// add on top in gfx950's unified file -- r5/r6 sat at 1 block/CU because
// arch+acc > 128. Projection is two-pass to cap acc at 64 AGPR).
// Wave w owns the CONTIGUOUS 32-row q-tile t = (w<4 ? w : 11-w)*32; the
// permutation balances per-SIMD causal work (chunk counts {1,4},{1,4},
// {2,3},{2,3} across the 4 SIMDs). The tile's two 16-row halves are
// interleaved in the chunk loop sharing every K-fragment load (2x ILP).
// 32-row-aligned tiles give stmax in {1,3} (always odd) so the P-scratch
// write range st<=stmax exactly covers PV's read range st<=(stmax|1) --
// the round-3 uninitialized-LDS hazard cannot occur here by construction.
// K row-major [256][64] bf16 (XOR-swizzled), Vt [64][256] bf16 (swizzled),
// per-wave 16x64 P scratch time-shared by the two halves.
__global__ __launch_bounds__(512, 2) void attn_head(const float* __restrict__ x,
                                                    const u16* __restrict__ WbT,
                                                    float* __restrict__ out) {
    __shared__ __align__(16) u16 Klds[TT * HH];      // 32 KB
    __shared__ __align__(16) u16 Vtlds[HH * TT];     // 32 KB
    __shared__ __align__(16) u16 Pscr[8 * 16 * 64];  // 16 KB

    const int tid = (int)threadIdx.x;
    const int lane = tid & 63;
    const int w = tid >> 6;
    const int c = lane & 15;
    const int g = lane >> 4;
    const int b = (int)blockIdx.x;
    const int gr = 32 * (w < 4 ? w : 11 - w);

    char* kbase = (char*)Klds;
    char* vbase = (char*)Vtlds;
    char* sbase = (char*)(Pscr + w * 1024);
    const float* xb = x + (size_t)b * TT * CC;
    const float* prow0 = xb + (size_t)(gr + c) * CC + 8 * g;
    const float* prow1 = xb + (size_t)(gr + 16 + c) * CC + 8 * g;

    short8 Qf[2][2];

    // ---------------- pass A: Q and K for both 16-row halves ----------------
    {
        f32x4 acc[2][2][4];  // [mat Q/K][half][nt] = 64 AGPR
#pragma unroll
        for (int m = 0; m < 2; ++m)
#pragma unroll
            for (int h = 0; h < 2; ++h)
#pragma unroll
                for (int nt = 0; nt < 4; ++nt)
                    acc[m][h][nt] = (f32x4){0.f, 0.f, 0.f, 0.f};

        for (int kt = 0; kt < 12; ++kt) {
            short8 a0 = load_afr(prow0 + 32 * kt);
            short8 a1 = load_afr(prow1 + 32 * kt);
#pragma unroll
            for (int mat = 0; mat < 2; ++mat)
#pragma unroll
                for (int nt = 0; nt < 4; ++nt) {
                    short8 bfr = *(const short8*)(WbT + (size_t)(((mat * 12 + kt) * 4 + nt) * 64 + lane) * 8);
                    acc[mat][0][nt] = mfma16x16x32(a0, bfr, acc[mat][0][nt]);
                    acc[mat][1][nt] = mfma16x16x32(a1, bfr, acc[mat][1][nt]);
                }
        }

        // Q: D-layout -> own K rows (scratch) -> B-fragments, per half
#pragma unroll
        for (int h = 0; h < 2; ++h) {
            const int qr = gr + 16 * h;
#pragma unroll
            for (int nt = 0; nt < 4; ++nt)
#pragma unroll
                for (int r = 0; r < 4; ++r) {
                    int q = qr + 4 * g + r;
                    int hh = 16 * nt + c;
                    *(u16*)(kbase + q * 128 + ((hh * 2) ^ ((q & 7) << 4))) = fbf(acc[0][h][nt][r]);
                }
#pragma unroll
            for (int kt = 0; kt < 2; ++kt) {
                int q = qr + c;
                Qf[h][kt] = *(const short8*)(kbase + q * 128 + ((64 * kt + 16 * g) ^ ((q & 7) << 4)));
            }
        }

        // K rows (overwrite Q scratch; same-wave DS ordering is program order)
#pragma unroll
        for (int h = 0; h < 2; ++h)
#pragma unroll
            for (int nt = 0; nt < 4; ++nt) {
                int hh = 16 * nt + c;
#pragma unroll
                for (int r = 0; r < 4; ++r) {
                    int s = gr + 16 * h + 4 * g + r;
                    *(u16*)(kbase + s * 128 + ((hh * 2) ^ ((s & 7) << 4))) = fbf(acc[1][h][nt][r]);
                }
            }
    }

    // ---------------- pass B: V for both halves ----------------
    {
        f32x4 accV[2][4];  // 32 AGPR
#pragma unroll
        for (int h = 0; h < 2; ++h)
#pragma unroll
            for (int nt = 0; nt < 4; ++nt)
                accV[h][nt] = (f32x4){0.f, 0.f, 0.f, 0.f};

        for (int kt = 0; kt < 12; ++kt) {
            short8 a0 = load_afr(prow0 + 32 * kt);
            short8 a1 = load_afr(prow1 + 32 * kt);
#pragma unroll
            for (int nt = 0; nt < 4; ++nt) {
                short8 bfr = *(const short8*)(WbT + (size_t)(((2 * 12 + kt) * 4 + nt) * 64 + lane) * 8);
                accV[0][nt] = mfma16x16x32(a0, bfr, accV[0][nt]);
                accV[1][nt] = mfma16x16x32(a1, bfr, accV[1][nt]);
            }
        }

#pragma unroll
        for (int h = 0; h < 2; ++h)
#pragma unroll
            for (int nt = 0; nt < 4; ++nt) {
                int hh = 16 * nt + c;
                int sb4 = gr + 16 * h + 4 * g;
                u64 pkv = (u64)cvtpk(accV[h][nt][0], accV[h][nt][1]) |
                          ((u64)cvtpk(accV[h][nt][2], accV[h][nt][3]) << 32);
                *(u64*)(vbase + hh * 512 + ((sb4 * 2) ^ ((hh & 7) << 4))) = pkv;
            }
    }

    __syncthreads();

    // ---------------- attention: two halves interleaved ----------------
    const int lastc = (gr + 31) >> 6;
    const int qg0 = gr + c, qg1 = gr + 16 + c;

    float m0r = -1e30f, l0r = 0.f, m1r = -1e30f, l1r = 0.f;
    f32x4 o[2][4];  // 32 AGPR
#pragma unroll
    for (int h = 0; h < 2; ++h)
#pragma unroll
        for (int ht = 0; ht < 4; ++ht)
            o[h][ht] = (f32x4){0.f, 0.f, 0.f, 0.f};

    for (int ci = 0; ci <= lastc; ++ci) {
        const int s0 = 64 * ci;
        int stx = (gr + 31 - s0) >> 4;
        const int stmax = stx > 3 ? 3 : stx;  // always odd: 1 or 3
        const bool needMask = (s0 + 63 > gr);

        // S^T: each K-fragment load feeds both halves (2x ILP)
        f32x4 SS[4][2];  // 32 AGPR
#pragma unroll
        for (int st = 0; st < 4; ++st) {
            SS[st][0] = (f32x4){0.f, 0.f, 0.f, 0.f};
            SS[st][1] = (f32x4){0.f, 0.f, 0.f, 0.f};
        }
#pragma unroll
        for (int kt = 0; kt < 2; ++kt)
#pragma unroll
            for (int st = 0; st < 4; ++st)
                if (st <= stmax) {
                    int s = s0 + 16 * st + c;
                    short8 kf = *(const short8*)(kbase + s * 128 + ((64 * kt + 16 * g) ^ ((s & 7) << 4)));
                    SS[st][0] = mfma16x16x32(kf, Qf[0][kt], SS[st][0]);
                    SS[st][1] = mfma16x16x32(kf, Qf[1][kt], SS[st][1]);
                }

        // mask (diagonal chunks only) + chunk max, both halves
        float mx0 = -1e30f, mx1 = -1e30f;
#pragma unroll
        for (int st = 0; st < 4; ++st)
            if (st <= stmax)
#pragma unroll
                for (int r = 0; r < 4; ++r) {
                    float v0 = SS[st][0][r], v1 = SS[st][1][r];
                    if (needMask) {
                        int sg = s0 + 16 * st + 4 * g + r;
                        v0 = (sg > qg0) ? -1e30f : v0;
                        v1 = (sg > qg1) ? -1e30f : v1;
                        SS[st][0][r] = v0;
                        SS[st][1][r] = v1;
                    }
                    mx0 = fmaxf(mx0, v0);
                    mx1 = fmaxf(mx1, v1);
                }
        mx0 = fmaxf(mx0, __shfl_xor(mx0, 16));
        mx0 = fmaxf(mx0, __shfl_xor(mx0, 32));
        mx1 = fmaxf(mx1, __shfl_xor(mx1, 16));
        mx1 = fmaxf(mx1, __shfl_xor(mx1, 32));

        float mn0 = fmaxf(m0r, mx0), mn1 = fmaxf(m1r, mx1);
        float fs0 = __expf(m0r - mn0), fs1 = __expf(m1r - mn1);
        m0r = mn0;
        m1r = mn1;

        float ls0 = 0.f, ls1 = 0.f;
#pragma unroll
        for (int st = 0; st < 4; ++st)
            if (st <= stmax)
#pragma unroll
                for (int r = 0; r < 4; ++r) {
                    float p0 = __expf(SS[st][0][r] - mn0);
                    float p1 = __expf(SS[st][1][r] - mn1);
                    SS[st][0][r] = p0;
                    SS[st][1][r] = p1;
                    ls0 += p0;
                    ls1 += p1;
                }
        ls0 += __shfl_xor(ls0, 16);
        ls0 += __shfl_xor(ls0, 32);
        ls1 += __shfl_xor(ls1, 16);
        ls1 += __shfl_xor(ls1, 32);
        l0r = l0r * fs0 + ls0;
        l1r = l1r * fs1 + ls1;

        // rescale O (row j=4g+r gets fs from lane c'=j)
        if (ci) {
#pragma unroll
            for (int r = 0; r < 4; ++r) {
                float fr0 = __shfl(fs0, 4 * g + r);
                float fr1 = __shfl(fs1, 4 * g + r);
#pragma unroll
                for (int ht = 0; ht < 4; ++ht) {
                    o[0][ht][r] *= fr0;
                    o[1][ht][r] *= fr1;
                }
            }
        }

        // PV per half through the shared 2KB scratch (same-wave DS order)
        const int ksmax = stmax >> 1;
#pragma unroll
        for (int h = 0; h < 2; ++h) {
#pragma unroll
            for (int st = 0; st < 4; ++st)
                if (st <= stmax) {
                    u64 pp = (u64)cvtpk(SS[st][h][0], SS[st][h][1]) |
                             ((u64)cvtpk(SS[st][h][2], SS[st][h][3]) << 32);
                    *(u64*)(sbase + c * 128 + ((32 * st + 8 * g) ^ ((c & 7) << 4))) = pp;
                }
#pragma unroll
            for (int ks = 0; ks < 2; ++ks)
                if (ks <= ksmax) {
                    short8 Pf = *(const short8*)(sbase + c * 128 + ((64 * ks + 16 * g) ^ ((c & 7) << 4)));
#pragma unroll
                    for (int ht = 0; ht < 4; ++ht) {
                        int hh = 16 * ht + c;
                        short8 vf = *(const short8*)(vbase + hh * 512 + ((2 * s0 + 64 * ks + 16 * g) ^ ((hh & 7) << 4)));
                        o[h][ht] = mfma16x16x32(Pf, vf, o[h][ht]);
                    }
                }
        }
    }

    // ---------------- epilogue: both halves ----------------
    float ri0 = 1.f / l0r, ri1 = 1.f / l1r;
    float* ob0 = out + ((size_t)b * TT + gr) * HH;
    float* ob1 = ob0 + 16 * HH;
#pragma unroll
    for (int r = 0; r < 4; ++r) {
        float rr0 = __shfl(ri0, 4 * g + r);
        float rr1 = __shfl(ri1, 4 * g + r);
#pragma unroll
        for (int ht = 0; ht < 4; ++ht) {
            ob0[(4 * g + r) * HH + 16 * ht + c] = o[0][ht][r] * rr0;
            ob1[(4 * g + r) * HH + 16 * ht + c] = o[1][ht][r] * rr1;
        }
    }
}

extern "C" void kernel_launch(void* const* d_in, const int* in_sizes, int n_in,
                              void* d_out, int out_size, void* d_ws, size_t ws_size,
                              hipStream_t stream) {
    (void)in_sizes; (void)n_in; (void)out_size; (void)ws_size;
    const float* x = (const float*)d_in[0];
    const float* Wk = (const float*)d_in[1];
    const float* Wq = (const float*)d_in[2];
    const float* Wv = (const float*)d_in[3];
    u16* WbT = (u16*)d_ws;
    float* out = (float*)d_out;

    prep_w<<<36, 256, 0, stream>>>(Wk, Wq, Wv, WbT);
    attn_head<<<NB, 512, 0, stream>>>(x, WbT, out);
}